// Round 11
// baseline (126.018 us; speedup 1.0000x reference)
//
#include <hip/hip_runtime.h>

// LayerStacks round 11: weights OUT of LDS -> 4 blocks/CU (32 waves/CU).
// Prep kernel packs W1/W2 into d_ws as f16 MFMA fragments (52 KB, L1/L2-hot).
// Main kernel (512 thr) keeps only mob/list/biases/transpose scratch in LDS
// (~19 KB) => occupancy doubles vs R9/R10 (which were both 16 waves/CU:
// weight tables pinned LDS at 55+ KB). Compute identical to R9/R10.

#define NB 6
#define BT 512
#define NW (BT / 64)

typedef _Float16 h2 __attribute__((ext_vector_type(2)));
typedef _Float16 h8 __attribute__((ext_vector_type(8)));
typedef float f4 __attribute__((ext_vector_type(4)));

#define GW1_ELEMS (NB * 2 * 4 * 4 * 9 * 8)    // 13824 f16
#define GW2_ELEMS (NB * 4 * 4 * 16 * 8)       // 12288 f16

__device__ __forceinline__ h2 pk2(float x, float y) {
    return __builtin_bit_cast(h2, __builtin_amdgcn_cvt_pkrtz(x, y));
}

__device__ __forceinline__ h8 pack8(const float4 a, const float4 b) {
    h2 p0 = pk2(a.x, a.y), p1 = pk2(a.z, a.w);
    h2 p2 = pk2(b.x, b.y), p3 = pk2(b.z, b.w);
    h8 r;
    r[0] = p0[0]; r[1] = p0[1]; r[2] = p1[0]; r[3] = p1[1];
    r[4] = p2[0]; r[5] = p2[1]; r[6] = p3[0]; r[7] = p3[1];
    return r;
}

__device__ __forceinline__ float actv(float v) {
    float u = fminf(fmaxf(v, 0.0f), 1.0f);
    return u * u * (255.0f / 256.0f);
}

// ---------------- prep: pack W1/W2 fragments into d_ws (f16) -----------------
__global__ __launch_bounds__(1024)
void k_pack(const float* __restrict__ W1b, const float* __restrict__ W1pa,
            const float* __restrict__ W2, const float* __restrict__ Wout,
            _Float16* __restrict__ gW1, _Float16* __restrict__ gW2)
{
    const int i0 = blockIdx.x * 1024 + threadIdx.x;
    const int stride = gridDim.x * 1024;

    // gW1: [b][st][t][qd][n<=8][i], value = n<8 ? W1x[n][k] : WoutSlice[k],
    // k = t*32 + qd*8 + i
    for (int e = i0; e < GW1_ELEMS; e += stride) {
        int i = e & 7;
        int rest = e >> 3;
        int n = rest % 9;   rest /= 9;
        int qd = rest & 3;  rest >>= 2;
        int t = rest & 3;   rest >>= 2;
        int st = rest & 1;
        int b = rest >> 1;
        int k = t * 32 + qd * 8 + i;
        float v;
        if (n < 8) {
            const float* Wx = st ? W1pa : W1b;
            v = Wx[b * 1032 + n * 129 + k];
        } else {
            v = st ? Wout[b * 320 + 192 + k] : Wout[b * 320 + 64 + k];
        }
        gW1[e] = (_Float16)v;
    }
    // gW2: [b][T][qd][j][i], n = T*16+j, k = qd*8+i, feature-interleaved cols
    for (int e = i0; e < GW2_ELEMS; e += stride) {
        int i = e & 7;
        int j = (e >> 3) & 15;
        int qd = (e >> 7) & 3;
        int T = (e >> 9) & 3;
        int b = e >> 11;
        int n = T * 16 + j;
        int k = qd * 8 + i;
        int u = k >> 1;
        int colw = (k & 1) ? (16 + u) : u;
        gW2[e] = (_Float16)W2[b * 2048 + n * 32 + colw];
    }
}

// ---------------- main -------------------------------------------------------
__global__ __launch_bounds__(BT, 8)
void layerstacks_mfma(const float* __restrict__ x_base,
                      const float* __restrict__ x_pa,
                      const float* __restrict__ mobility,
                      const int*   __restrict__ ply,
                      const float* __restrict__ b1b,
                      const float* __restrict__ b1pa,
                      const float* __restrict__ W1b,
                      const float* __restrict__ W1pa,
                      const float* __restrict__ b2,
                      const float* __restrict__ Wout,
                      const float* __restrict__ bout,
                      const _Float16* __restrict__ gW1,
                      const _Float16* __restrict__ gW2,
                      float* __restrict__ out)
{
    __shared__ float sWo0[NB][64];
    __shared__ float sB2[NB][64];
    __shared__ float sB1[NB][4][8];
    __shared__ float sBout[NB];
    __shared__ float sMob[BT];
    __shared__ int   sList[BT + NB * 16];
    __shared__ __align__(16) char sL1[NW * 1280];
    __shared__ int sCnt[8], sCur[8], sTb[40];
    __shared__ int sNt;

    const int tid   = threadIdx.x;
    const int lane  = tid & 63;
    const int w     = tid >> 6;
    const int gbase = blockIdx.x * BT;

    // ---------------- phase 0: small staging --------------------------------
    if (tid < 8) { sCnt[tid] = 0; }
    for (int e = tid; e < NB * 64; e += BT) {
        int b = e >> 6, n = e & 63;
        sWo0[b][n] = Wout[b * 320 + n];
        sB2[b][n]  = b2[e];
    }
    if (tid < NB * 4 * 8) {
        int n = tid & 7, which = (tid >> 3) & 3, b = tid >> 5;
        float v;
        if (which == 0)      v = b1b[b * 8 + n];
        else if (which == 1) v = b1pa[b * 8 + n];
        else if (which == 2) v = W1b [b * 1032 + n * 129 + 128];
        else                 v = W1pa[b * 1032 + n * 129 + 128];
        sB1[b][which][n] = v;
    }
    if (tid < NB) sBout[tid] = bout[tid];
    sMob[tid] = fminf(mobility[gbase + tid] * (7.0f / 255.0f), 1.0f);
    for (int e = tid; e < BT + NB * 16; e += BT) sList[e] = -1;

    const int bb = ply[gbase + tid] / 10;
    __syncthreads();

    // ---------------- phase 1: ballot-aggregated counts ---------------------
    #pragma unroll
    for (int b = 0; b < NB; ++b) {
        unsigned long long mk = __ballot(bb == b);
        if (bb == b) {
            int lead = __ffsll((long long)mk) - 1;
            if (lane == lead) atomicAdd(&sCnt[b], __popcll(mk));
        }
    }
    __syncthreads();

    // ---------------- phase 2: offsets + tile->bucket map -------------------
    if (tid == 0) {
        int off = 0, tt = 0;
        for (int b = 0; b < NB; ++b) {
            sCur[b] = off;
            int ntl = (sCnt[b] + 15) >> 4;
            for (int q = 0; q < ntl; ++q) sTb[tt++] = b;
            off += ntl << 4;
        }
        sNt = tt;
    }
    __syncthreads();

    // ---------------- phase 3: scatter local indices ------------------------
    #pragma unroll
    for (int b = 0; b < NB; ++b) {
        unsigned long long mk = __ballot(bb == b);
        if (bb == b) {
            int lead = __ffsll((long long)mk) - 1;
            int pfx = __popcll(mk & ((1ull << lane) - 1ull));
            int base = 0;
            if (lane == lead) base = atomicAdd(&sCur[b], __popcll(mk));
            base = __shfl(base, lead);
            sList[base + pfx] = tid;
        }
    }
    __syncthreads();

    // ---------------- main: per-wave MFMA tiles -----------------------------
    const int ntiles = sNt;
    const int col = lane & 15;
    const int qd  = lane >> 4;
    char* lb = sL1 + w * 1280;

    for (int tl = w; tl < ntiles; tl += NW) {
        const int bkt = sTb[tl];
        const int t16 = tl << 4;

        const int sl0 = sList[t16 + qd * 4 + 0];
        const int sl1 = sList[t16 + qd * 4 + 1];
        const int sl2 = sList[t16 + qd * 4 + 2];
        const int sl3 = sList[t16 + qd * 4 + 3];
        int sA = sList[t16 + col];
        if (sA < 0) sA = sList[t16];

        const float* xbrow = x_base + (size_t)(gbase + sA) * 128 + qd * 8;
        const float* xprow = x_pa   + (size_t)(gbase + sA) * 128 + qd * 8;
        const float4 b00 = *(const float4*)(xbrow + 0);
        const float4 b01 = *(const float4*)(xbrow + 4);
        const float4 b10 = *(const float4*)(xbrow + 32);
        const float4 b11 = *(const float4*)(xbrow + 36);
        const float4 b20 = *(const float4*)(xbrow + 64);
        const float4 b21 = *(const float4*)(xbrow + 68);
        const float4 b30 = *(const float4*)(xbrow + 96);
        const float4 b31 = *(const float4*)(xbrow + 100);
        const float4 q00 = *(const float4*)(xprow + 0);
        const float4 q01 = *(const float4*)(xprow + 4);
        const float4 q10 = *(const float4*)(xprow + 32);
        const float4 q11 = *(const float4*)(xprow + 36);
        const float4 q20 = *(const float4*)(xprow + 64);
        const float4 q21 = *(const float4*)(xprow + 68);
        const float4 q30 = *(const float4*)(xprow + 96);
        const float4 q31 = *(const float4*)(xprow + 100);

        const float mob0 = (sl0 >= 0) ? sMob[sl0] : 0.0f;
        const float mob1 = (sl1 >= 0) ? sMob[sl1] : 0.0f;
        const float mob2 = (sl2 >= 0) ? sMob[sl2] : 0.0f;
        const float mob3 = (sl3 >= 0) ? sMob[sl3] : 0.0f;

        const int c7 = col & 7;
        const bool a8 = (col < 8);
        const int ncl = a8 ? col : 8;

        // ---- weight fragments from GLOBAL (L1/L2-hot packed blob) ----------
        const _Float16* w1p = gW1 + (size_t)bkt * (2 * 4 * 4 * 9 * 8);
        const _Float16* w1a = w1p + (size_t)qd * 72 + (size_t)ncl * 8;       // st=0
        const _Float16* w1q = w1a + (size_t)(4 * 4 * 9 * 8);                 // st=1
        const h8 wa0 = *(const h8*)(w1a + 0 * 288);
        const h8 wa1 = *(const h8*)(w1a + 1 * 288);
        const h8 wa2 = *(const h8*)(w1a + 2 * 288);
        const h8 wa3 = *(const h8*)(w1a + 3 * 288);
        const h8 wp0 = *(const h8*)(w1q + 0 * 288);
        const h8 wp1 = *(const h8*)(w1q + 1 * 288);
        const h8 wp2 = *(const h8*)(w1q + 2 * 288);
        const h8 wp3 = *(const h8*)(w1q + 3 * 288);

        const float bb1 = sB1[bkt][0][c7], bp1 = sB1[bkt][1][c7];
        const float mwb = sB1[bkt][2][c7], mwp = sB1[bkt][3][c7];
        f4 cb, cp;
        cb[0] = a8 ? bb1 + mwb * mob0 : 0.0f;
        cb[1] = a8 ? bb1 + mwb * mob1 : 0.0f;
        cb[2] = a8 ? bb1 + mwb * mob2 : 0.0f;
        cb[3] = a8 ? bb1 + mwb * mob3 : 0.0f;
        cp[0] = a8 ? bp1 + mwp * mob0 : 0.0f;
        cp[1] = a8 ? bp1 + mwp * mob1 : 0.0f;
        cp[2] = a8 ? bp1 + mwp * mob2 : 0.0f;
        cp[3] = a8 ? bp1 + mwp * mob3 : 0.0f;

        cb = __builtin_amdgcn_mfma_f32_16x16x32_f16(pack8(b00, b01), wa0, cb, 0, 0, 0);
        cp = __builtin_amdgcn_mfma_f32_16x16x32_f16(pack8(q00, q01), wp0, cp, 0, 0, 0);
        cb = __builtin_amdgcn_mfma_f32_16x16x32_f16(pack8(b10, b11), wa1, cb, 0, 0, 0);
        cp = __builtin_amdgcn_mfma_f32_16x16x32_f16(pack8(q10, q11), wp1, cp, 0, 0, 0);
        cb = __builtin_amdgcn_mfma_f32_16x16x32_f16(pack8(b20, b21), wa2, cb, 0, 0, 0);
        cp = __builtin_amdgcn_mfma_f32_16x16x32_f16(pack8(q20, q21), wp2, cp, 0, 0, 0);
        cb = __builtin_amdgcn_mfma_f32_16x16x32_f16(pack8(b30, b31), wa3, cb, 0, 0, 0);
        cp = __builtin_amdgcn_mfma_f32_16x16x32_f16(pack8(q30, q31), wp3, cp, 0, 0, 0);

        if (col < 8) {
            #pragma unroll
            for (int r = 0; r < 4; ++r) {
                const int row = qd * 4 + r;
                float v = cb[r];
                *(h2*)(lb + row * 80 + col * 4) =
                    pk2(fminf(v * v * (255.0f / 256.0f), 1.0f),
                        fminf(fmaxf(v, 0.0f), 1.0f));
                v = cp[r];
                *(h2*)(lb + row * 80 + 32 + col * 4) =
                    pk2(fminf(v * v * (255.0f / 256.0f), 1.0f),
                        fminf(fmaxf(v, 0.0f), 1.0f));
            }
        } else if (col == 8) {
            #pragma unroll
            for (int r = 0; r < 4; ++r) {
                const int row = qd * 4 + r;
                *(float*)(lb + row * 80 + 64) = cb[r];
                *(float*)(lb + row * 80 + 68) = cp[r];
            }
        }

        const h8 a2 = *(const h8*)(lb + col * 80 + qd * 16);
        const _Float16* w2p = gW2 + (size_t)bkt * (4 * 4 * 16 * 8)
                                  + (size_t)qd * 128 + (size_t)col * 8;
        const float s0 = sB2[bkt][col];
        const float s1 = sB2[bkt][16 + col];
        const float s2 = sB2[bkt][32 + col];
        const float s3 = sB2[bkt][48 + col];
        f4 c20 = {s0, s0, s0, s0};
        f4 c21 = {s1, s1, s1, s1};
        f4 c22 = {s2, s2, s2, s2};
        f4 c23 = {s3, s3, s3, s3};
        c20 = __builtin_amdgcn_mfma_f32_16x16x32_f16(a2, *(const h8*)(w2p + 0 * 512), c20, 0, 0, 0);
        c21 = __builtin_amdgcn_mfma_f32_16x16x32_f16(a2, *(const h8*)(w2p + 1 * 512), c21, 0, 0, 0);
        c22 = __builtin_amdgcn_mfma_f32_16x16x32_f16(a2, *(const h8*)(w2p + 2 * 512), c22, 0, 0, 0);
        c23 = __builtin_amdgcn_mfma_f32_16x16x32_f16(a2, *(const h8*)(w2p + 3 * 512), c23, 0, 0, 0);

        const float wo0 = sWo0[bkt][col];
        const float wo1 = sWo0[bkt][16 + col];
        const float wo2 = sWo0[bkt][32 + col];
        const float wo3 = sWo0[bkt][48 + col];
        float p0 = actv(c20[0]) * wo0 + actv(c21[0]) * wo1 + actv(c22[0]) * wo2 + actv(c23[0]) * wo3;
        float p1 = actv(c20[1]) * wo0 + actv(c21[1]) * wo1 + actv(c22[1]) * wo2 + actv(c23[1]) * wo3;
        float p2 = actv(c20[2]) * wo0 + actv(c21[2]) * wo1 + actv(c22[2]) * wo2 + actv(c23[2]) * wo3;
        float p3 = actv(c20[3]) * wo0 + actv(c21[3]) * wo1 + actv(c22[3]) * wo2 + actv(c23[3]) * wo3;
        #pragma unroll
        for (int m = 1; m < 16; m <<= 1) {
            p0 += __shfl_xor(p0, m, 64);
            p1 += __shfl_xor(p1, m, 64);
            p2 += __shfl_xor(p2, m, 64);
            p3 += __shfl_xor(p3, m, 64);
        }

        if (col == 0) {
            const float bo = sBout[bkt];
            if (sl0 >= 0)
                out[gbase + sl0] = bo + *(const float*)(lb + (qd * 4 + 0) * 80 + 64)
                                      + *(const float*)(lb + (qd * 4 + 0) * 80 + 68) + p0;
            if (sl1 >= 0)
                out[gbase + sl1] = bo + *(const float*)(lb + (qd * 4 + 1) * 80 + 64)
                                      + *(const float*)(lb + (qd * 4 + 1) * 80 + 68) + p1;
            if (sl2 >= 0)
                out[gbase + sl2] = bo + *(const float*)(lb + (qd * 4 + 2) * 80 + 64)
                                      + *(const float*)(lb + (qd * 4 + 2) * 80 + 68) + p2;
            if (sl3 >= 0)
                out[gbase + sl3] = bo + *(const float*)(lb + (qd * 4 + 3) * 80 + 64)
                                      + *(const float*)(lb + (qd * 4 + 3) * 80 + 68) + p3;
        }
    }
}

extern "C" void kernel_launch(void* const* d_in, const int* in_sizes, int n_in,
                              void* d_out, int out_size, void* d_ws, size_t ws_size,
                              hipStream_t stream) {
    const float* x_base   = (const float*)d_in[0];
    const float* x_pa     = (const float*)d_in[1];
    const float* mobility = (const float*)d_in[2];
    const int*   ply      = (const int*)d_in[3];
    const float* W1b      = (const float*)d_in[4];
    const float* b1b      = (const float*)d_in[5];
    const float* W1pa     = (const float*)d_in[6];
    const float* b1pa     = (const float*)d_in[7];
    const float* W2       = (const float*)d_in[8];
    const float* b2       = (const float*)d_in[9];
    const float* Wout     = (const float*)d_in[10];
    const float* bout     = (const float*)d_in[11];
    float* out = (float*)d_out;

    _Float16* gW1 = (_Float16*)d_ws;
    _Float16* gW2 = gW1 + GW1_ELEMS;

    const int B = in_sizes[3];              // 262144 (multiple of 512)
    k_pack<<<16, 1024, 0, stream>>>(W1b, W1pa, W2, Wout, gW1, gW2);
    layerstacks_mfma<<<B / BT, BT, 0, stream>>>(
        x_base, x_pa, mobility, ply, b1b, b1pa, W1b, W1pa, b2, Wout, bout,
        gW1, gW2, out);
}

// Round 12
// 69.031 us; speedup vs baseline: 1.8255x; 1.8255x over previous
//
#include <hip/hip_runtime.h>

// LayerStacks round 12: R10 (best, 60.8us) + sched_barrier load clustering.
// R9-R11 evidence: compiler sinks x loads next to consumers (VGPR pinned ~64,
// all pipes <15busy) => ~2 loads in flight. __builtin_amdgcn_sched_barrier(0)
// after the load cluster forbids the sink: 16 global + 8 LDS-weight loads all
// issue before any pack/MFMA => one latency window per tile instead of ~8.
// Everything else byte-identical to R10.

#define NB 6
#define BT 512
#define NW (BT / 64)

typedef _Float16 h2 __attribute__((ext_vector_type(2)));
typedef _Float16 h8 __attribute__((ext_vector_type(8)));
typedef float f4 __attribute__((ext_vector_type(4)));

__device__ __forceinline__ h2 pk2(float x, float y) {
    return __builtin_bit_cast(h2, __builtin_amdgcn_cvt_pkrtz(x, y));
}

__device__ __forceinline__ h8 pack8(const float4 a, const float4 b) {
    h2 p0 = pk2(a.x, a.y), p1 = pk2(a.z, a.w);
    h2 p2 = pk2(b.x, b.y), p3 = pk2(b.z, b.w);
    h8 r;
    r[0] = p0[0]; r[1] = p0[1]; r[2] = p1[0]; r[3] = p1[1];
    r[4] = p2[0]; r[5] = p2[1]; r[6] = p3[0]; r[7] = p3[1];
    return r;
}

__device__ __forceinline__ float actv(float v) {
    float u = fminf(fmaxf(v, 0.0f), 1.0f);
    return u * u * (255.0f / 256.0f);
}

__global__ __launch_bounds__(BT, 4)
void layerstacks_mfma(const float* __restrict__ x_base,
                      const float* __restrict__ x_pa,
                      const float* __restrict__ mobility,
                      const int*   __restrict__ ply,
                      const float* __restrict__ W1b,
                      const float* __restrict__ b1b,
                      const float* __restrict__ W1pa,
                      const float* __restrict__ b1pa,
                      const float* __restrict__ W2,
                      const float* __restrict__ b2,
                      const float* __restrict__ Wout,
                      const float* __restrict__ bout,
                      float* __restrict__ out)
{
    __shared__ __align__(16) _Float16 sW1[NB][2][4][4][9][8];   // 27.6 KB
    __shared__ __align__(16) _Float16 sW2[NB][4][4][16][8];     // 24.6 KB
    __shared__ float sWo0[NB][64];
    __shared__ float sB2[NB][64];
    __shared__ float sB1[NB][4][8];
    __shared__ float sBout[NB];
    __shared__ float sMob[BT];
    __shared__ int   sList[BT + NB * 16];
    __shared__ __align__(16) char sL1[NW * 1280];
    __shared__ int sCnt[8], sCur[8], sTb[40];
    __shared__ int sNt;

    const int tid   = threadIdx.x;
    const int lane  = tid & 63;
    const int w     = tid >> 6;
    const int gbase = blockIdx.x * BT;

    // ---------------- phase 0: staging --------------------------------------
    if (tid < 8) { sCnt[tid] = 0; }

    for (int e = tid; e < NB * 2 * 4 * 4 * 9 * 8; e += BT) {
        int i = e & 7;
        int rest = e >> 3;
        int n = rest % 9;   rest /= 9;
        int kb = rest & 3;  rest >>= 2;
        int t = rest & 3;   rest >>= 2;
        int st = rest & 1;
        int b = rest >> 1;
        int k = t * 32 + kb * 8 + i;
        float v;
        if (n < 8) {
            const float* Wx = st ? W1pa : W1b;
            v = Wx[b * 1032 + n * 129 + k];
        } else {
            v = st ? Wout[b * 320 + 192 + k] : Wout[b * 320 + 64 + k];
        }
        sW1[b][st][t][kb][n][i] = (_Float16)v;
    }
    for (int e = tid; e < NB * 4 * 4 * 16 * 8; e += BT) {
        int i = e & 7;
        int j = (e >> 3) & 15;
        int kb = (e >> 7) & 3;
        int T = (e >> 9) & 3;
        int b = e >> 11;
        int n = T * 16 + j;
        int k = kb * 8 + i;
        int u = k >> 1;
        int colw = (k & 1) ? (16 + u) : u;
        sW2[b][T][kb][j][i] = (_Float16)W2[b * 2048 + n * 32 + colw];
    }
    for (int e = tid; e < NB * 64; e += BT) {
        int b = e >> 6, n = e & 63;
        sWo0[b][n] = Wout[b * 320 + n];
        sB2[b][n]  = b2[e];
    }
    if (tid < NB * 4 * 8) {
        int n = tid & 7, which = (tid >> 3) & 3, b = tid >> 5;
        float v;
        if (which == 0)      v = b1b[b * 8 + n];
        else if (which == 1) v = b1pa[b * 8 + n];
        else if (which == 2) v = W1b [b * 1032 + n * 129 + 128];
        else                 v = W1pa[b * 1032 + n * 129 + 128];
        sB1[b][which][n] = v;
    }
    if (tid < NB) sBout[tid] = bout[tid];
    sMob[tid] = fminf(mobility[gbase + tid] * (7.0f / 255.0f), 1.0f);
    for (int e = tid; e < BT + NB * 16; e += BT) sList[e] = -1;

    const int bb = ply[gbase + tid] / 10;
    __syncthreads();

    // ---------------- phase 1: ballot-aggregated counts ---------------------
    #pragma unroll
    for (int b = 0; b < NB; ++b) {
        unsigned long long mk = __ballot(bb == b);
        if (bb == b) {
            int lead = __ffsll((long long)mk) - 1;
            if (lane == lead) atomicAdd(&sCnt[b], __popcll(mk));
        }
    }
    __syncthreads();

    // ---------------- phase 2: offsets + tile->bucket map -------------------
    if (tid == 0) {
        int off = 0, tt = 0;
        for (int b = 0; b < NB; ++b) {
            sCur[b] = off;
            int ntl = (sCnt[b] + 15) >> 4;
            for (int q = 0; q < ntl; ++q) sTb[tt++] = b;
            off += ntl << 4;
        }
        sNt = tt;
    }
    __syncthreads();

    // ---------------- phase 3: scatter local indices ------------------------
    #pragma unroll
    for (int b = 0; b < NB; ++b) {
        unsigned long long mk = __ballot(bb == b);
        if (bb == b) {
            int lead = __ffsll((long long)mk) - 1;
            int pfx = __popcll(mk & ((1ull << lane) - 1ull));
            int base = 0;
            if (lane == lead) base = atomicAdd(&sCur[b], __popcll(mk));
            base = __shfl(base, lead);
            sList[base + pfx] = tid;
        }
    }
    __syncthreads();

    // ---------------- main: per-wave MFMA tiles -----------------------------
    const int ntiles = sNt;
    const int col = lane & 15;
    const int qd  = lane >> 4;
    char* lb = sL1 + w * 1280;

    for (int tl = w; tl < ntiles; tl += NW) {
        const int bkt = sTb[tl];
        const int t16 = tl << 4;

        const int sl0 = sList[t16 + qd * 4 + 0];
        const int sl1 = sList[t16 + qd * 4 + 1];
        const int sl2 = sList[t16 + qd * 4 + 2];
        const int sl3 = sList[t16 + qd * 4 + 3];
        int sA = sList[t16 + col];
        if (sA < 0) sA = sList[t16];

        // ==== LOAD CLUSTER: 16 global + 8 LDS weights + mob/bias ============
        const float* xbrow = x_base + (size_t)(gbase + sA) * 128 + qd * 8;
        const float* xprow = x_pa   + (size_t)(gbase + sA) * 128 + qd * 8;
        const float4 b00 = *(const float4*)(xbrow + 0);
        const float4 b01 = *(const float4*)(xbrow + 4);
        const float4 b10 = *(const float4*)(xbrow + 32);
        const float4 b11 = *(const float4*)(xbrow + 36);
        const float4 b20 = *(const float4*)(xbrow + 64);
        const float4 b21 = *(const float4*)(xbrow + 68);
        const float4 b30 = *(const float4*)(xbrow + 96);
        const float4 b31 = *(const float4*)(xbrow + 100);
        const float4 q00 = *(const float4*)(xprow + 0);
        const float4 q01 = *(const float4*)(xprow + 4);
        const float4 q10 = *(const float4*)(xprow + 32);
        const float4 q11 = *(const float4*)(xprow + 36);
        const float4 q20 = *(const float4*)(xprow + 64);
        const float4 q21 = *(const float4*)(xprow + 68);
        const float4 q30 = *(const float4*)(xprow + 96);
        const float4 q31 = *(const float4*)(xprow + 100);

        const int c7 = col & 7;
        const bool a8 = (col < 8);
        const int ncl = a8 ? col : 8;

        const h8 wa0 = *(const h8*)&sW1[bkt][0][0][qd][ncl][0];
        const h8 wa1 = *(const h8*)&sW1[bkt][0][1][qd][ncl][0];
        const h8 wa2 = *(const h8*)&sW1[bkt][0][2][qd][ncl][0];
        const h8 wa3 = *(const h8*)&sW1[bkt][0][3][qd][ncl][0];
        const h8 wp0 = *(const h8*)&sW1[bkt][1][0][qd][ncl][0];
        const h8 wp1 = *(const h8*)&sW1[bkt][1][1][qd][ncl][0];
        const h8 wp2 = *(const h8*)&sW1[bkt][1][2][qd][ncl][0];
        const h8 wp3 = *(const h8*)&sW1[bkt][1][3][qd][ncl][0];

        const float mob0 = (sl0 >= 0) ? sMob[sl0] : 0.0f;
        const float mob1 = (sl1 >= 0) ? sMob[sl1] : 0.0f;
        const float mob2 = (sl2 >= 0) ? sMob[sl2] : 0.0f;
        const float mob3 = (sl3 >= 0) ? sMob[sl3] : 0.0f;
        const float bb1 = sB1[bkt][0][c7], bp1 = sB1[bkt][1][c7];
        const float mwb = sB1[bkt][2][c7], mwp = sB1[bkt][3][c7];

        // Pin: nothing below may move above, loads may not sink below.
        __builtin_amdgcn_sched_barrier(0);
        // ====================================================================

        f4 cb, cp;
        cb[0] = a8 ? bb1 + mwb * mob0 : 0.0f;
        cb[1] = a8 ? bb1 + mwb * mob1 : 0.0f;
        cb[2] = a8 ? bb1 + mwb * mob2 : 0.0f;
        cb[3] = a8 ? bb1 + mwb * mob3 : 0.0f;
        cp[0] = a8 ? bp1 + mwp * mob0 : 0.0f;
        cp[1] = a8 ? bp1 + mwp * mob1 : 0.0f;
        cp[2] = a8 ? bp1 + mwp * mob2 : 0.0f;
        cp[3] = a8 ? bp1 + mwp * mob3 : 0.0f;

        cb = __builtin_amdgcn_mfma_f32_16x16x32_f16(pack8(b00, b01), wa0, cb, 0, 0, 0);
        cp = __builtin_amdgcn_mfma_f32_16x16x32_f16(pack8(q00, q01), wp0, cp, 0, 0, 0);
        cb = __builtin_amdgcn_mfma_f32_16x16x32_f16(pack8(b10, b11), wa1, cb, 0, 0, 0);
        cp = __builtin_amdgcn_mfma_f32_16x16x32_f16(pack8(q10, q11), wp1, cp, 0, 0, 0);
        cb = __builtin_amdgcn_mfma_f32_16x16x32_f16(pack8(b20, b21), wa2, cb, 0, 0, 0);
        cp = __builtin_amdgcn_mfma_f32_16x16x32_f16(pack8(q20, q21), wp2, cp, 0, 0, 0);
        cb = __builtin_amdgcn_mfma_f32_16x16x32_f16(pack8(b30, b31), wa3, cb, 0, 0, 0);
        cp = __builtin_amdgcn_mfma_f32_16x16x32_f16(pack8(q30, q31), wp3, cp, 0, 0, 0);

        if (col < 8) {
            #pragma unroll
            for (int r = 0; r < 4; ++r) {
                const int row = qd * 4 + r;
                float v = cb[r];
                *(h2*)(lb + row * 80 + col * 4) =
                    pk2(fminf(v * v * (255.0f / 256.0f), 1.0f),
                        fminf(fmaxf(v, 0.0f), 1.0f));
                v = cp[r];
                *(h2*)(lb + row * 80 + 32 + col * 4) =
                    pk2(fminf(v * v * (255.0f / 256.0f), 1.0f),
                        fminf(fmaxf(v, 0.0f), 1.0f));
            }
        } else if (col == 8) {
            #pragma unroll
            for (int r = 0; r < 4; ++r) {
                const int row = qd * 4 + r;
                *(float*)(lb + row * 80 + 64) = cb[r];
                *(float*)(lb + row * 80 + 68) = cp[r];
            }
        }

        const h8 a2 = *(const h8*)(lb + col * 80 + qd * 16);
        const float s0 = sB2[bkt][col];
        const float s1 = sB2[bkt][16 + col];
        const float s2 = sB2[bkt][32 + col];
        const float s3 = sB2[bkt][48 + col];
        f4 c20 = {s0, s0, s0, s0};
        f4 c21 = {s1, s1, s1, s1};
        f4 c22 = {s2, s2, s2, s2};
        f4 c23 = {s3, s3, s3, s3};
        c20 = __builtin_amdgcn_mfma_f32_16x16x32_f16(a2, *(const h8*)&sW2[bkt][0][qd][col][0], c20, 0, 0, 0);
        c21 = __builtin_amdgcn_mfma_f32_16x16x32_f16(a2, *(const h8*)&sW2[bkt][1][qd][col][0], c21, 0, 0, 0);
        c22 = __builtin_amdgcn_mfma_f32_16x16x32_f16(a2, *(const h8*)&sW2[bkt][2][qd][col][0], c22, 0, 0, 0);
        c23 = __builtin_amdgcn_mfma_f32_16x16x32_f16(a2, *(const h8*)&sW2[bkt][3][qd][col][0], c23, 0, 0, 0);

        const float wo0 = sWo0[bkt][col];
        const float wo1 = sWo0[bkt][16 + col];
        const float wo2 = sWo0[bkt][32 + col];
        const float wo3 = sWo0[bkt][48 + col];
        float p0 = actv(c20[0]) * wo0 + actv(c21[0]) * wo1 + actv(c22[0]) * wo2 + actv(c23[0]) * wo3;
        float p1 = actv(c20[1]) * wo0 + actv(c21[1]) * wo1 + actv(c22[1]) * wo2 + actv(c23[1]) * wo3;
        float p2 = actv(c20[2]) * wo0 + actv(c21[2]) * wo1 + actv(c22[2]) * wo2 + actv(c23[2]) * wo3;
        float p3 = actv(c20[3]) * wo0 + actv(c21[3]) * wo1 + actv(c22[3]) * wo2 + actv(c23[3]) * wo3;
        #pragma unroll
        for (int m = 1; m < 16; m <<= 1) {
            p0 += __shfl_xor(p0, m, 64);
            p1 += __shfl_xor(p1, m, 64);
            p2 += __shfl_xor(p2, m, 64);
            p3 += __shfl_xor(p3, m, 64);
        }

        if (col == 0) {
            const float bo = sBout[bkt];
            if (sl0 >= 0)
                out[gbase + sl0] = bo + *(const float*)(lb + (qd * 4 + 0) * 80 + 64)
                                      + *(const float*)(lb + (qd * 4 + 0) * 80 + 68) + p0;
            if (sl1 >= 0)
                out[gbase + sl1] = bo + *(const float*)(lb + (qd * 4 + 1) * 80 + 64)
                                      + *(const float*)(lb + (qd * 4 + 1) * 80 + 68) + p1;
            if (sl2 >= 0)
                out[gbase + sl2] = bo + *(const float*)(lb + (qd * 4 + 2) * 80 + 64)
                                      + *(const float*)(lb + (qd * 4 + 2) * 80 + 68) + p2;
            if (sl3 >= 0)
                out[gbase + sl3] = bo + *(const float*)(lb + (qd * 4 + 3) * 80 + 64)
                                      + *(const float*)(lb + (qd * 4 + 3) * 80 + 68) + p3;
        }
    }
}

extern "C" void kernel_launch(void* const* d_in, const int* in_sizes, int n_in,
                              void* d_out, int out_size, void* d_ws, size_t ws_size,
                              hipStream_t stream) {
    const float* x_base   = (const float*)d_in[0];
    const float* x_pa     = (const float*)d_in[1];
    const float* mobility = (const float*)d_in[2];
    const int*   ply      = (const int*)d_in[3];
    const float* W1b      = (const float*)d_in[4];
    const float* b1b      = (const float*)d_in[5];
    const float* W1pa     = (const float*)d_in[6];
    const float* b1pa     = (const float*)d_in[7];
    const float* W2       = (const float*)d_in[8];
    const float* b2       = (const float*)d_in[9];
    const float* Wout     = (const float*)d_in[10];
    const float* bout     = (const float*)d_in[11];
    float* out = (float*)d_out;

    const int B = in_sizes[3];              // 262144 (multiple of 512)
    const int blocks = B / BT;              // 512
    layerstacks_mfma<<<blocks, BT, 0, stream>>>(
        x_base, x_pa, mobility, ply, W1b, b1b, W1pa, b1pa, W2, b2, Wout, bout, out);
}